// Round 10
// baseline (138.124 us; speedup 1.0000x reference)
//
#include <hip/hip_runtime.h>
#include <math.h>
#include <stdint.h>

#define BATCH 64
#define SEQ   101
#define HID   512
#define NKQ   100      // N*K
#define KCLS  10
#define INV_TEMP 0.04419417382415922f   // 1/sqrt(512)

typedef short bf16x8 __attribute__((ext_vector_type(8)));
typedef float f32x4  __attribute__((ext_vector_type(4)));

// truncation split: x == hi + lo to ~2^-17 rel
__device__ inline void split_bf16(float x, short& hi, short& lo) {
    uint32_t u = __builtin_bit_cast(uint32_t, x);
    hi = (short)(u >> 16);
    float hf = __builtin_bit_cast(float, u & 0xFFFF0000u);
    float l  = x - hf;
    lo = (short)(__builtin_bit_cast(uint32_t, l) >> 16);
}
// round-to-nearest-even bf16 (single-plane operands)
__device__ inline short rtn_bf16(float x) {
    uint32_t u = __builtin_bit_cast(uint32_t, x);
    return (short)((u + 0x7FFFu + ((u >> 16) & 1u)) >> 16);
}

#define KST 72    // khi/qhi/qlo row stride (shorts), 144 B
#define VT  152   // vth/vtl row stride (shorts), 304 B (16B-aligned rows)

// One block = (b, 16 query rows). grid 448 flat (b = id&63 -> XCD affinity),
// 512 thr = 8 waves. LDS pool aliased: P1 {khi,qhi,qlo} / P3 {vth,vtl}.
// P1: k staged RTN-bf16 (128 j-rows) + q hi/lo -> ds_read_b128 -> MFMA.
// P2: softmax -> attn global + A-fragments (ah/al/mh) in LDS.
// P3: 8 h-chunks of 64: scatter-stage v^T hi/lo; waves 0-3 MFMA one 16-h tile
//     each (K=128 complete per chunk) + immediate region-decomposed epilogue.
__global__ __launch_bounds__(512, 4)
void fused_attn(const float* __restrict__ q, const float* __restrict__ k,
                const float* __restrict__ v, const float* __restrict__ aw,
                float* __restrict__ out, float* __restrict__ attn) {
    __shared__ float sc[16][132];        // 8448 B
    __shared__ short ah_s[16][136];      // 4352 B
    __shared__ short al_s[16][136];      // 4352 B
    __shared__ short mh_s[16][136];      // 4352 B
    __shared__ __align__(16) char pool[38912];
    short (*khi)[KST] = (short(*)[KST])pool;             // 128x72x2 = 18432
    short (*qhi)[KST] = (short(*)[KST])(pool + 18432);   // 16x72x2  =  2304
    short (*qlo)[KST] = (short(*)[KST])(pool + 20736);   // 16x72x2  =  2304
    short (*vth)[VT]  = (short(*)[VT])pool;              // 64x152x2 = 19456
    short (*vtl)[VT]  = (short(*)[VT])(pool + 19456);    // 64x152x2 = 19456

    const int b   = blockIdx.x & 63;
    const int i0  = (blockIdx.x >> 6) * 16;
    const int tid = threadIdx.x;
    const int wv  = tid >> 6, lane = tid & 63;
    const int m   = lane & 15;           // A-row / B-col / C-col index
    const int kq  = (lane >> 4) * 8;     // k-offset within 32-step
    const int rq  = (lane >> 4) * 4;     // C-row quad base
    const int j0w = wv * 16;

    const float* qb = q + (size_t)b * SEQ * HID;
    const float* kb = k + (size_t)b * SEQ * HID;
    const float* vb = v + (size_t)b * SEQ * HID;

    // ---------------- Phase 1: QK^T (LDS-staged, 2 MFMA / 32-k) -------------
    f32x4 acc = {};
    for (int kc = 0; kc < HID; kc += 64) {
        #pragma unroll
        for (int s = 0; s < 4; ++s) {
            const int f = tid + s * 512;           // 0..2047
            const int r = f >> 4, c = (f & 15) << 2;
            float4 x = make_float4(0.f, 0.f, 0.f, 0.f);
            if (r < SEQ) x = *(const float4*)(kb + (size_t)r * HID + kc + c);
            short4 hv;
            hv.x = rtn_bf16(x.x); hv.y = rtn_bf16(x.y);
            hv.z = rtn_bf16(x.z); hv.w = rtn_bf16(x.w);
            *(short4*)&khi[r][c] = hv;
        }
        if (tid < 256) {
            const int r = tid >> 4, c = (tid & 15) << 2;
            const int gi = i0 + r;
            float4 x = make_float4(0.f, 0.f, 0.f, 0.f);
            if (gi < SEQ) x = *(const float4*)(qb + (size_t)gi * HID + kc + c);
            short4 hv, lv;
            split_bf16(x.x, hv.x, lv.x);
            split_bf16(x.y, hv.y, lv.y);
            split_bf16(x.z, hv.z, lv.z);
            split_bf16(x.w, hv.w, lv.w);
            *(short4*)&qhi[r][c] = hv;
            *(short4*)&qlo[r][c] = lv;
        }
        __syncthreads();
        #pragma unroll
        for (int ks = 0; ks < 64; ks += 32) {
            const bf16x8 qH = *(const bf16x8*)&qhi[m][ks + kq];
            const bf16x8 qL = *(const bf16x8*)&qlo[m][ks + kq];
            const bf16x8 kH = *(const bf16x8*)&khi[j0w + m][ks + kq];
            acc = __builtin_amdgcn_mfma_f32_16x16x32_bf16(qH, kH, acc, 0, 0, 0);
            acc = __builtin_amdgcn_mfma_f32_16x16x32_bf16(qL, kH, acc, 0, 0, 0);
        }
        __syncthreads();
    }
    #pragma unroll
    for (int r = 0; r < 4; ++r)
        sc[rq + r][j0w + m] = acc[r];
    __syncthreads();

    // ---------------- Phase 2: softmax + attn + A-fragments -----------------
    {
        const int row = tid >> 5, t32 = tid & 31;
        const int gi  = i0 + row;
        float mx = -1e30f;
        for (int j = t32; j < SEQ; j += 32) {
            float s = sc[row][j] * INV_TEMP;
            sc[row][j] = s;
            mx = fmaxf(mx, s);
        }
        #pragma unroll
        for (int off = 1; off < 32; off <<= 1) mx = fmaxf(mx, __shfl_xor(mx, off));
        float sum = 0.f;
        for (int j = t32; j < SEQ; j += 32) {
            float e = __expf(sc[row][j] - mx);
            sc[row][j] = e;
            sum += e;
        }
        #pragma unroll
        for (int off = 1; off < 32; off <<= 1) sum += __shfl_xor(sum, off);
        const float inv = 1.f / sum;
        const int ci = gi / KCLS;
        float* arow = attn + ((size_t)b * SEQ + gi) * SEQ;
        for (int j = t32; j < SEQ; j += 32) {
            float a = sc[row][j] * inv;
            sc[row][j] = a;
            if (gi < SEQ) arow[j] = a;
            short h, l; split_bf16(a, h, l);
            ah_s[row][j] = h; al_s[row][j] = l;
            mh_s[row][j] = ((j / KCLS) == ci) ? h : (short)0;
        }
        for (int j = SEQ + t32; j < 136; j += 32) {   // zero pad cols [101,136)
            ah_s[row][j] = 0; al_s[row][j] = 0; mh_s[row][j] = 0;
        }
    }
    __syncthreads();

    // ---------------- Phase 3: PV per 64-h chunk + epilogue -----------------
    bf16x8 Ah[4], Al[4], Mh[4];
    if (wv < 4) {
        #pragma unroll
        for (int s = 0; s < 4; ++s) {
            Ah[s] = *(const bf16x8*)&ah_s[m][s * 32 + kq];
            Al[s] = *(const bf16x8*)&al_s[m][s * 32 + kq];
            Mh[s] = *(const bf16x8*)&mh_s[m][s * 32 + kq];
        }
    }
    for (int hc = 0; hc < HID; hc += 64) {
        // scatter-stage v^T hi/lo: 128 j-rows (zero-padded) x 64 h
        #pragma unroll
        for (int s = 0; s < 4; ++s) {
            const int f = tid + s * 512;           // 0..2047
            const int j = f >> 4;                  // 0..127
            const int c = (f & 15) << 2;           // h-local 0..60
            float4 x = make_float4(0.f, 0.f, 0.f, 0.f);
            if (j < SEQ) x = *(const float4*)(vb + (size_t)j * HID + hc + c);
            short h0, l0, h1, l1, h2, l2, h3, l3;
            split_bf16(x.x, h0, l0);
            split_bf16(x.y, h1, l1);
            split_bf16(x.z, h2, l2);
            split_bf16(x.w, h3, l3);
            vth[c + 0][j] = h0; vtl[c + 0][j] = l0;
            vth[c + 1][j] = h1; vtl[c + 1][j] = l1;
            vth[c + 2][j] = h2; vtl[c + 2][j] = l2;
            vth[c + 3][j] = h3; vtl[c + 3][j] = l3;
        }
        __syncthreads();
        if (wv < 4) {
            f32x4 T = {}, U = {};
            #pragma unroll
            for (int s = 0; s < 4; ++s) {
                const bf16x8 Bh = *(const bf16x8*)&vth[wv * 16 + m][s * 32 + kq];
                const bf16x8 Bl = *(const bf16x8*)&vtl[wv * 16 + m][s * 32 + kq];
                T = __builtin_amdgcn_mfma_f32_16x16x32_bf16(Ah[s], Bh, T, 0, 0, 0);
                T = __builtin_amdgcn_mfma_f32_16x16x32_bf16(Ah[s], Bl, T, 0, 0, 0);
                T = __builtin_amdgcn_mfma_f32_16x16x32_bf16(Al[s], Bh, T, 0, 0, 0);
                U = __builtin_amdgcn_mfma_f32_16x16x32_bf16(Mh[s], Bh, U, 0, 0, 0);
            }
            const int h = hc + wv * 16 + m;
            const float w0 = aw[0 * HID + h], w1 = aw[1 * HID + h], w2 = aw[2 * HID + h];
            const float w3 = aw[3 * HID + h], w4 = aw[4 * HID + h], w5 = aw[5 * HID + h];
            const float vN = vb[(size_t)NKQ * HID + h];
            #pragma unroll
            for (int r = 0; r < 4; ++r) {
                const int il = rq + r;
                const int i  = i0 + il;
                if (i >= SEQ) continue;
                const float aiN = sc[il][NKQ];
                float o;
                if (i < NKQ) {
                    const float aii = sc[il][i];
                    const float vi  = vb[(size_t)i * HID + h];
                    o = w2 * T[r] + (w1 - w2) * U[r] + (w0 - w1) * aii * vi + (w3 - w2) * aiN * vN;
                } else {
                    o = w4 * T[r] + (w5 - w4) * aiN * vN;
                }
                out[((size_t)b * SEQ + i) * HID + h] = o;
            }
        }
        __syncthreads();
    }
}

extern "C" void kernel_launch(void* const* d_in, const int* in_sizes, int n_in,
                              void* d_out, int out_size, void* d_ws, size_t ws_size,
                              hipStream_t stream) {
    const float* q  = (const float*)d_in[0];
    const float* k  = (const float*)d_in[1];
    const float* v  = (const float*)d_in[2];
    const float* aw = (const float*)d_in[3];
    float* out  = (float*)d_out;
    float* attn = out + (size_t)BATCH * SEQ * HID;   // tuple output: [out | attn]

    fused_attn<<<dim3(448), dim3(512), 0, stream>>>(q, k, v, aw, out, attn);
}